// Round 10
// baseline (211.079 us; speedup 1.0000x reference)
//
#include <hip/hip_runtime.h>
#include <cstdint>

#define NN 2048
#define LOG2E 1.4426950408889634f

typedef __attribute__((ext_vector_type(8))) short bf16x8;
typedef __attribute__((ext_vector_type(4))) float f32x4;

__device__ __forceinline__ unsigned short f2bf(float x){
  union { float f; unsigned u; } v; v.f = x;
  unsigned r = v.u + 0x7FFFu + ((v.u >> 16) & 1u);
  return (unsigned short)(r >> 16);
}
__device__ __forceinline__ unsigned pack2(float a, float b){
  return (unsigned)f2bf(a) | ((unsigned)f2bf(b) << 16);
}
// pack two already-truncated uints (value & 0xFFFF0000) in one v_perm
__device__ __forceinline__ unsigned permpack(unsigned hi, unsigned lo){
  return __builtin_amdgcn_perm(hi, lo, 0x07060302u);
}

// ---------------- K0: adj->bitmask (blocks 0..2047) + W^T bf16 (blocks 2048..2303) ----------------
__global__ __launch_bounds__(256) void k_prep(const float* __restrict__ adj,
                                              const float* __restrict__ W,
                                              unsigned long long* __restrict__ ab,
                                              unsigned short* __restrict__ Wt){
  int tid = threadIdx.x;
  if (blockIdx.x < 2048){
    int i = blockIdx.x;
    int w = tid >> 6, lane = tid & 63;
    #pragma unroll
    for (int seg = 0; seg < 8; seg++){
      int j = seg * 256 + tid;
      unsigned long long m = __ballot(adj[(size_t)i * NN + j] != 0.0f);
      if (lane == 0) ab[i * 32 + seg * 4 + w] = m;
    }
  } else {
    int g = (blockIdx.x - 2048) * 256 + tid;   // g = o*256 + k
    int o = g >> 8, k = g & 255;
    Wt[g] = f2bf(W[k * 256 + o]);
  }
}

// ---------------- K1: fused Wh=h@W -> s1,s2 (log2e-scaled) + WhT(bf16) ----------------
// grid 512 (b=bid&7 XCD-affine, 2 blocks/CU), 256 threads (4 waves).
// BM=32, BO=256 (wave owns 64 cols). Frag-linear As (conflict-free), double-
// buffered As + B-frags, one barrier per k-tile.
__global__ __launch_bounds__(256, 2) void k_fused_gemm(const float* __restrict__ h,
                                                       const unsigned short* __restrict__ Wt,
                                                       const float* __restrict__ a,
                                                       unsigned short* __restrict__ WhT,
                                                       float* __restrict__ s1c,
                                                       float* __restrict__ s2c){
  __shared__ __align__(16) unsigned char As[2 * 4096];     // 2 bufs x 4 frags x 1 KB
  __shared__ __align__(16) unsigned short Ts[256 * 36];    // 18432 B (o-major, stride 36: 2-way max)
  __shared__ float s1p[4][32], s2p[4][32];                 //  1024 B
  const int tid = threadIdx.x;
  const int bid = blockIdx.x;
  const int b  = bid & 7;
  const int i0 = (bid >> 3) * 32;
  const size_t r0 = (size_t)b * NN + i0;
  const int w = tid >> 6, lane = tid & 63, lhi = lane >> 4, llo = lane & 15;
  const int wc = w * 64;
  const int sit = w & 1, skk = w >> 1;          // staging role: frag (sit,skk)
  const int srow = sit * 16 + llo;
  const int skol = skk * 32 + lhi * 8;

  f32x4 acc[2][4];
  #pragma unroll
  for (int i = 0; i < 2; i++)
    #pragma unroll
    for (int j = 0; j < 4; j++){ acc[i][j][0]=0.f; acc[i][j][1]=0.f; acc[i][j][2]=0.f; acc[i][j][3]=0.f; }

  // prefetch all 4 k-tiles of this thread's A-frag slice
  float4 hv[4][2];
  #pragma unroll
  for (int t = 0; t < 4; t++){
    const float* hp = h + (r0 + srow) * 256 + t * 64 + skol;
    hv[t][0] = *(const float4*)hp;
    hv[t][1] = *(const float4*)(hp + 4);
  }

  auto loadB = [&](int k0, bf16x8* dst){        // 8 frags [ot][kk]
    #pragma unroll
    for (int ot = 0; ot < 4; ot++)
      #pragma unroll
      for (int kk = 0; kk < 2; kk++)
        dst[ot * 2 + kk] = *(const bf16x8*)(Wt + (size_t)(wc + ot * 16 + llo) * 256 + k0 + kk * 32 + lhi * 8);
  };
  bf16x8 bfr[2][8];
  loadB(0, bfr[0]);

  #pragma unroll
  for (int t = 0; t < 4; t++){
    uint4 q = make_uint4(pack2(hv[t][0].x, hv[t][0].y), pack2(hv[t][0].z, hv[t][0].w),
                         pack2(hv[t][1].x, hv[t][1].y), pack2(hv[t][1].z, hv[t][1].w));
    *(uint4*)&As[(t & 1) * 4096 + (sit * 2 + skk) * 1024 + lane * 16] = q;  // lane-linear
    __syncthreads();
    if (t < 3) loadB((t + 1) * 64, bfr[(t + 1) & 1]);
    bf16x8 af[2][2];                            // [kk][it], lane-linear reads
    #pragma unroll
    for (int kk = 0; kk < 2; kk++)
      #pragma unroll
      for (int it = 0; it < 2; it++)
        af[kk][it] = *(const bf16x8*)&As[(t & 1) * 4096 + (it * 2 + kk) * 1024 + lane * 16];
    #pragma unroll
    for (int kk = 0; kk < 2; kk++)
      #pragma unroll
      for (int it = 0; it < 2; it++)
        #pragma unroll
        for (int ot = 0; ot < 4; ot++)
          acc[it][ot] = __builtin_amdgcn_mfma_f32_16x16x32_bf16(af[kk][it], bfr[t & 1][ot * 2 + kk], acc[it][ot], 0, 0, 0);
  }

  // ---- epilogue 1: s1/s2 partial dots (log2e folded) ----
  float a1v[4], a2v[4];
  #pragma unroll
  for (int ot = 0; ot < 4; ot++){
    a1v[ot] = a[wc + ot * 16 + llo] * LOG2E;
    a2v[ot] = a[256 + wc + ot * 16 + llo] * LOG2E;
  }
  #pragma unroll
  for (int it = 0; it < 2; it++){
    #pragma unroll
    for (int q = 0; q < 4; q++){
      float p1 = 0.f, p2 = 0.f;
      #pragma unroll
      for (int ot = 0; ot < 4; ot++){
        p1 += acc[it][ot][q] * a1v[ot];
        p2 += acc[it][ot][q] * a2v[ot];
      }
      #pragma unroll
      for (int o = 1; o < 16; o <<= 1){ p1 += __shfl_xor(p1, o); p2 += __shfl_xor(p2, o); }
      if (llo == 0){
        s1p[w][it * 16 + lhi * 4 + q] = p1;
        s2p[w][it * 16 + lhi * 4 + q] = p2;
      }
    }
  }

  // ---- epilogue 2: transpose acc (bf16, round) into Ts[o][i_local] ----
  #pragma unroll
  for (int it = 0; it < 2; it++){
    #pragma unroll
    for (int ot = 0; ot < 4; ot++){
      int o = wc + ot * 16 + llo;
      uint2 u = make_uint2(pack2(acc[it][ot][0], acc[it][ot][1]),
                           pack2(acc[it][ot][2], acc[it][ot][3]));
      *(uint2*)&Ts[o * 36 + it * 16 + lhi * 4] = u;
    }
  }
  __syncthreads();

  if (tid < 32){
    float t1 = 0.f, t2 = 0.f;
    #pragma unroll
    for (int g = 0; g < 4; g++){ t1 += s1p[g][tid]; t2 += s2p[g][tid]; }
    s1c[r0 + tid] = t1;
    s2c[r0 + tid] = t2;
  }
  #pragma unroll
  for (int p = 0; p < 4; p++){
    int o = p * 64 + (tid >> 2), col = (tid & 3) * 8;
    *(uint4*)(WhT + (size_t)(b * 256 + o) * 2048 + i0 + col) = *(const uint4*)&Ts[o * 36 + col];
  }
}

// ---------------- K2: h' = softmax(P) @ Wh  (private-P, (2x,2x) corner) ----------------
// grid 512 (b=bid&7 XCD-affine, 2 blocks/CU), 256 threads (4 waves).
// Block = 32 rows x 256 cols; wave (wi,wo) = 16 rows x 128 cols (it=1, ot=8, kk=2).
// P-redundancy 2x (wo pair), B-redundancy 2x but sibling wave on same CU -> L1 hit.
// Zero K-loop barriers. Denominator via ones-MFMA into acc_l (idle MFMA pipe):
// D-layout gives 1/acc_l[q] directly as the scale for row lhi*4+q.
__global__ __launch_bounds__(256, 2) void k_attn(const float* __restrict__ s1c,
                                                 const float* __restrict__ s2c,
                                                 const unsigned short* __restrict__ WhT,
                                                 const unsigned long long* __restrict__ ab,
                                                 float* __restrict__ out){
  __shared__ __align__(16) float s2s[2048];                  // 8192 B
  __shared__ __align__(16) unsigned char bitsB[32 * 264];    // 8448 B
  __shared__ float s1s[32], red[4];
  const int tid = threadIdx.x;
  const int bid = blockIdx.x;
  const int b = bid & 7, i0 = (bid >> 3) * 32;
  const int w = tid >> 6, lane = tid & 63, lhi = lane >> 4, llo = lane & 15;
  const int wi = w & 1, wo = w >> 1;
  const int co = wo * 128;                       // wave's col base
  const int prow = wi * 16 + llo;                // P row this lane computes

  // ---- preamble: stage s2 (+max), s1 tile, adjacency mask rows ----
  float4 v0 = ((const float4*)(s2c + (size_t)b * NN))[tid];
  float4 v1 = ((const float4*)(s2c + (size_t)b * NN))[tid + 256];
  ((float4*)s2s)[tid]       = v0;
  ((float4*)s2s)[tid + 256] = v1;
  float vmax = fmaxf(fmaxf(fmaxf(v0.x, v0.y), fmaxf(v0.z, v0.w)),
                     fmaxf(fmaxf(v1.x, v1.y), fmaxf(v1.z, v1.w)));
  #pragma unroll
  for (int o = 32; o; o >>= 1) vmax = fmaxf(vmax, __shfl_xor(vmax, o));
  if (lane == 0) red[w] = vmax;
  if (tid < 32) s1s[tid] = s1c[(size_t)b * NN + i0 + tid];
  #pragma unroll
  for (int k = 0; k < 4; k++){
    int g = k * 256 + tid;                       // 0..1023 mask words
    unsigned long long mw = ab[(size_t)i0 * 32 + g];
    *(unsigned long long*)&bitsB[(g >> 5) * 264 + (g & 31) * 8] = mw;
  }
  __syncthreads();
  float m2 = fmaxf(fmaxf(red[0], red[1]), fmaxf(red[2], red[3]));

  const float s1v = s1s[prow];
  const float xm = s1v + m2;
  const float mv = fmaxf(xm, 0.2f * xm);         // upper bound on row max (lrelu monotone)
  const float c1 = s1v - mv;                     // y = max(s2+c1, 0.2*s2+c2)
  const float c2 = 0.2f * s1v - mv;

  f32x4 acc[8], acc_l;
  #pragma unroll
  for (int j = 0; j < 8; j++){ acc[j][0]=0.f; acc[j][1]=0.f; acc[j][2]=0.f; acc[j][3]=0.f; }
  acc_l[0]=0.f; acc_l[1]=0.f; acc_l[2]=0.f; acc_l[3]=0.f;

  const uint4 onesq = make_uint4(0x3F803F80u, 0x3F803F80u, 0x3F803F80u, 0x3F803F80u);
  const bf16x8 onesf = *(const bf16x8*)&onesq;

  for (int t = 0; t < 32; t++){
    // ---- B frags (single-buffered; latency covered by computeP + sibling wave) ----
    bf16x8 bf[16];
    #pragma unroll
    for (int ot = 0; ot < 8; ot++)
      #pragma unroll
      for (int kk = 0; kk < 2; kk++)
        bf[ot * 2 + kk] = *(const bf16x8*)(WhT + (size_t)(b * 256 + co + ot * 16 + llo) * 2048 + t * 64 + kk * 32 + lhi * 8);
    // ---- P fragment in registers (16 elems/lane) ----
    bf16x8 af[2];
    #pragma unroll
    for (int kk = 0; kk < 2; kk++){
      unsigned bits = bitsB[prow * 264 + t * 8 + kk * 4 + lhi];
      const float* sp = &s2s[t * 64 + kk * 32 + lhi * 8];
      float4 xa = *(const float4*)sp;
      float4 xb = *(const float4*)(sp + 4);
      float xs[8] = {xa.x, xa.y, xa.z, xa.w, xb.x, xb.y, xb.z, xb.w};
      unsigned pu[8];
      #pragma unroll
      for (int e = 0; e < 8; e++){
        float s2v = xs[e];
        float y = fmaxf(s2v + c1, __builtin_fmaf(0.2f, s2v, c2));
        float p = __builtin_amdgcn_exp2f(y);
        unsigned msel = ((bits >> e) & 1u) ? 0xFFFF0000u : 0u;
        pu[e] = __float_as_uint(p) & msel;       // mask + truncate in one AND
      }
      uint4 q = make_uint4(permpack(pu[1], pu[0]), permpack(pu[3], pu[2]),
                           permpack(pu[5], pu[4]), permpack(pu[7], pu[6]));
      af[kk] = *(bf16x8*)&q;
    }
    // ---- MFMA: numerator (16) + denominator ones-column (2) ----
    #pragma unroll
    for (int kk = 0; kk < 2; kk++){
      acc_l = __builtin_amdgcn_mfma_f32_16x16x32_bf16(af[kk], onesf, acc_l, 0, 0, 0);
      #pragma unroll
      for (int ot = 0; ot < 8; ot++)
        acc[ot] = __builtin_amdgcn_mfma_f32_16x16x32_bf16(af[kk], bf[ot * 2 + kk], acc[ot], 0, 0, 0);
    }
  }

  // ---- epilogue: scale by 1/rowsum (acc_l[q] is rowsum of row lhi*4+q, all cols equal) ----
  #pragma unroll
  for (int q = 0; q < 4; q++){
    float lv = 1.0f / acc_l[q];
    int row = i0 + wi * 16 + lhi * 4 + q;
    #pragma unroll
    for (int ot = 0; ot < 8; ot++)
      out[(size_t)(b * NN + row) * 256 + co + ot * 16 + llo] = acc[ot][q] * lv;
  }
}

extern "C" void kernel_launch(void* const* d_in, const int* in_sizes, int n_in,
                              void* d_out, int out_size, void* d_ws, size_t ws_size,
                              hipStream_t stream) {
  const float* h   = (const float*)d_in[0];
  const float* adj = (const float*)d_in[1];
  const float* W   = (const float*)d_in[2];
  const float* a   = (const float*)d_in[3];
  float* out = (float*)d_out;

  char* ws = (char*)d_ws;
  unsigned short* WhT      = (unsigned short*)(ws);                 // 8,388,608 B
  unsigned short* Wt       = (unsigned short*)(ws + 8388608);       //   131,072 B
  unsigned long long* ab   = (unsigned long long*)(ws + 8519680);   //   524,288 B
  float* s1c               = (float*)(ws + 9043968);                //    65,536 B
  float* s2c               = (float*)(ws + 9109504);                //    65,536 B

  hipLaunchKernelGGL(k_prep,       dim3(2304), dim3(256), 0, stream, adj, W, ab, Wt);
  hipLaunchKernelGGL(k_fused_gemm, dim3(512),  dim3(256), 0, stream, h, Wt, a, WhT, s1c, s2c);
  hipLaunchKernelGGL(k_attn,       dim3(512),  dim3(256), 0, stream, s1c, s2c, WhT, ab, out);
}

// Round 11
// 134.652 us; speedup vs baseline: 1.5676x; 1.5676x over previous
//
#include <hip/hip_runtime.h>
#include <cstdint>

#define NN 2048
#define LOG2E 1.4426950408889634f

typedef __attribute__((ext_vector_type(8))) short bf16x8;
typedef __attribute__((ext_vector_type(4))) float f32x4;

__device__ __forceinline__ unsigned short f2bf(float x){
  union { float f; unsigned u; } v; v.f = x;
  unsigned r = v.u + 0x7FFFu + ((v.u >> 16) & 1u);
  return (unsigned short)(r >> 16);
}
__device__ __forceinline__ unsigned pack2(float a, float b){
  return (unsigned)f2bf(a) | ((unsigned)f2bf(b) << 16);
}
// pack two already-truncated uints (value & 0xFFFF0000) in one v_perm
__device__ __forceinline__ unsigned permpack(unsigned hi, unsigned lo){
  return __builtin_amdgcn_perm(hi, lo, 0x07060302u);
}

// ---------------- K0: adj->bitmask (blocks 0..2047) + W^T bf16 (blocks 2048..2303) ----------------
__global__ __launch_bounds__(256) void k_prep(const float* __restrict__ adj,
                                              const float* __restrict__ W,
                                              unsigned long long* __restrict__ ab,
                                              unsigned short* __restrict__ Wt){
  int tid = threadIdx.x;
  if (blockIdx.x < 2048){
    int i = blockIdx.x;
    int w = tid >> 6, lane = tid & 63;
    #pragma unroll
    for (int seg = 0; seg < 8; seg++){
      int j = seg * 256 + tid;
      unsigned long long m = __ballot(adj[(size_t)i * NN + j] != 0.0f);
      if (lane == 0) ab[i * 32 + seg * 4 + w] = m;
    }
  } else {
    int g = (blockIdx.x - 2048) * 256 + tid;   // g = o*256 + k
    int o = g >> 8, k = g & 255;
    Wt[g] = f2bf(W[k * 256 + o]);
  }
}

// ---------------- K1: fused Wh=h@W -> s1,s2 (log2e-scaled) + WhT (FRAG-LINEAR bf16) ----------------
// grid 512 (b=bid&7 XCD-affine, 2 blocks/CU), 256 threads (4 waves).
// BM=32, BO=256. Epilogue stores WhT as 1KB MFMA B-fragments:
//   frag F = otile*64 + jt32 (per batch, 1024 frags); lane l's 16B at F*1024 + l*16
//   holding WhT[o=otile*16+llo][j=jt32*32+lhi*8+e].
__global__ __launch_bounds__(256, 2) void k_fused_gemm(const float* __restrict__ h,
                                                       const unsigned short* __restrict__ Wt,
                                                       const float* __restrict__ a,
                                                       unsigned short* __restrict__ WhT,
                                                       float* __restrict__ s1c,
                                                       float* __restrict__ s2c){
  __shared__ __align__(16) unsigned char As[2 * 4096];     // 2 bufs x 4 frags x 1 KB
  __shared__ __align__(16) unsigned short Ts[256 * 36];    // 18432 B (o-major, stride 36)
  __shared__ float s1p[4][32], s2p[4][32];                 //  1024 B
  const int tid = threadIdx.x;
  const int bid = blockIdx.x;
  const int b  = bid & 7;
  const int i0 = (bid >> 3) * 32;
  const size_t r0 = (size_t)b * NN + i0;
  const int w = tid >> 6, lane = tid & 63, lhi = lane >> 4, llo = lane & 15;
  const int wc = w * 64;
  const int sit = w & 1, skk = w >> 1;          // staging role: frag (sit,skk)
  const int srow = sit * 16 + llo;
  const int skol = skk * 32 + lhi * 8;

  f32x4 acc[2][4];
  #pragma unroll
  for (int i = 0; i < 2; i++)
    #pragma unroll
    for (int j = 0; j < 4; j++){ acc[i][j][0]=0.f; acc[i][j][1]=0.f; acc[i][j][2]=0.f; acc[i][j][3]=0.f; }

  // prefetch all 4 k-tiles of this thread's A-frag slice
  float4 hv[4][2];
  #pragma unroll
  for (int t = 0; t < 4; t++){
    const float* hp = h + (r0 + srow) * 256 + t * 64 + skol;
    hv[t][0] = *(const float4*)hp;
    hv[t][1] = *(const float4*)(hp + 4);
  }

  auto loadB = [&](int k0, bf16x8* dst){        // 8 frags [ot][kk]
    #pragma unroll
    for (int ot = 0; ot < 4; ot++)
      #pragma unroll
      for (int kk = 0; kk < 2; kk++)
        dst[ot * 2 + kk] = *(const bf16x8*)(Wt + (size_t)(wc + ot * 16 + llo) * 256 + k0 + kk * 32 + lhi * 8);
  };
  bf16x8 bfr[2][8];
  loadB(0, bfr[0]);

  #pragma unroll
  for (int t = 0; t < 4; t++){
    uint4 q = make_uint4(pack2(hv[t][0].x, hv[t][0].y), pack2(hv[t][0].z, hv[t][0].w),
                         pack2(hv[t][1].x, hv[t][1].y), pack2(hv[t][1].z, hv[t][1].w));
    *(uint4*)&As[(t & 1) * 4096 + (sit * 2 + skk) * 1024 + lane * 16] = q;  // lane-linear
    __syncthreads();
    if (t < 3) loadB((t + 1) * 64, bfr[(t + 1) & 1]);
    bf16x8 af[2][2];                            // [kk][it], lane-linear reads
    #pragma unroll
    for (int kk = 0; kk < 2; kk++)
      #pragma unroll
      for (int it = 0; it < 2; it++)
        af[kk][it] = *(const bf16x8*)&As[(t & 1) * 4096 + (it * 2 + kk) * 1024 + lane * 16];
    #pragma unroll
    for (int kk = 0; kk < 2; kk++)
      #pragma unroll
      for (int it = 0; it < 2; it++)
        #pragma unroll
        for (int ot = 0; ot < 4; ot++)
          acc[it][ot] = __builtin_amdgcn_mfma_f32_16x16x32_bf16(af[kk][it], bfr[t & 1][ot * 2 + kk], acc[it][ot], 0, 0, 0);
  }

  // ---- epilogue 1: s1/s2 partial dots (log2e folded) ----
  float a1v[4], a2v[4];
  #pragma unroll
  for (int ot = 0; ot < 4; ot++){
    a1v[ot] = a[wc + ot * 16 + llo] * LOG2E;
    a2v[ot] = a[256 + wc + ot * 16 + llo] * LOG2E;
  }
  #pragma unroll
  for (int it = 0; it < 2; it++){
    #pragma unroll
    for (int q = 0; q < 4; q++){
      float p1 = 0.f, p2 = 0.f;
      #pragma unroll
      for (int ot = 0; ot < 4; ot++){
        p1 += acc[it][ot][q] * a1v[ot];
        p2 += acc[it][ot][q] * a2v[ot];
      }
      #pragma unroll
      for (int o = 1; o < 16; o <<= 1){ p1 += __shfl_xor(p1, o); p2 += __shfl_xor(p2, o); }
      if (llo == 0){
        s1p[w][it * 16 + lhi * 4 + q] = p1;
        s2p[w][it * 16 + lhi * 4 + q] = p2;
      }
    }
  }

  // ---- epilogue 2: transpose acc (bf16, round) into Ts[o][i_local] ----
  #pragma unroll
  for (int it = 0; it < 2; it++){
    #pragma unroll
    for (int ot = 0; ot < 4; ot++){
      int o = wc + ot * 16 + llo;
      uint2 u = make_uint2(pack2(acc[it][ot][0], acc[it][ot][1]),
                           pack2(acc[it][ot][2], acc[it][ot][3]));
      *(uint2*)&Ts[o * 36 + it * 16 + lhi * 4] = u;
    }
  }
  __syncthreads();

  if (tid < 32){
    float t1 = 0.f, t2 = 0.f;
    #pragma unroll
    for (int g = 0; g < 4; g++){ t1 += s1p[g][tid]; t2 += s2p[g][tid]; }
    s1c[r0 + tid] = t1;
    s2c[r0 + tid] = t2;
  }
  // ---- frag-linear WhT write: 16 frags, thread (w,lane) writes frag p*4+w ----
  const int jt = i0 >> 5;                        // jtile32 index
  #pragma unroll
  for (int p = 0; p < 4; p++){
    int otile = p * 4 + w;
    uint4 d = *(const uint4*)&Ts[(otile * 16 + llo) * 36 + lhi * 8];  // 8 shorts contiguous
    size_t F = (size_t)b * 1024 + otile * 64 + jt;
    *(uint4*)(WhT + F * 512 + lane * 8) = d;     // fully coalesced 1KB/frag
  }
}

// ---------------- K2: h' = softmax(P) @ Wh  (private-P, frag-linear B, no barriers) ----------------
// grid 512 (b=bid&7, 2 blocks/CU), 256 threads (4 waves).
// Block = 32 rows x 256 cols; wave (wi,wo) = 16 rows x 128 cols.
// B-frags loaded as coalesced 1KB fragments (base + lane*16), double-buffered.
// Denominator via ones-MFMA into acc_l.
__global__ __launch_bounds__(256, 2) void k_attn(const float* __restrict__ s1c,
                                                 const float* __restrict__ s2c,
                                                 const unsigned short* __restrict__ WhT,
                                                 const unsigned long long* __restrict__ ab,
                                                 float* __restrict__ out){
  __shared__ __align__(16) float s2s[2048];                  // 8192 B
  __shared__ __align__(16) unsigned char bitsB[32 * 264];    // 8448 B
  __shared__ float s1s[32], red[4];
  const int tid = threadIdx.x;
  const int bid = blockIdx.x;
  const int b = bid & 7, i0 = (bid >> 3) * 32;
  const int w = tid >> 6, lane = tid & 63, lhi = lane >> 4, llo = lane & 15;
  const int wi = w & 1, wo = w >> 1;
  const int co = wo * 128;                       // wave's col base
  const int prow = wi * 16 + llo;                // P row this lane computes

  // ---- preamble: stage s2 (+max), s1 tile, adjacency mask rows ----
  float4 v0 = ((const float4*)(s2c + (size_t)b * NN))[tid];
  float4 v1 = ((const float4*)(s2c + (size_t)b * NN))[tid + 256];
  ((float4*)s2s)[tid]       = v0;
  ((float4*)s2s)[tid + 256] = v1;
  float vmax = fmaxf(fmaxf(fmaxf(v0.x, v0.y), fmaxf(v0.z, v0.w)),
                     fmaxf(fmaxf(v1.x, v1.y), fmaxf(v1.z, v1.w)));
  #pragma unroll
  for (int o = 32; o; o >>= 1) vmax = fmaxf(vmax, __shfl_xor(vmax, o));
  if (lane == 0) red[w] = vmax;
  if (tid < 32) s1s[tid] = s1c[(size_t)b * NN + i0 + tid];
  #pragma unroll
  for (int k = 0; k < 4; k++){
    int g = k * 256 + tid;                       // 0..1023 mask words
    unsigned long long mw = ab[(size_t)i0 * 32 + g];
    *(unsigned long long*)&bitsB[(g >> 5) * 264 + (g & 31) * 8] = mw;
  }
  __syncthreads();
  float m2 = fmaxf(fmaxf(red[0], red[1]), fmaxf(red[2], red[3]));

  const float s1v = s1s[prow];
  const float xm = s1v + m2;
  const float mv = fmaxf(xm, 0.2f * xm);         // upper bound on row max (lrelu monotone)
  const float c1 = s1v - mv;                     // y = max(s2+c1, 0.2*s2+c2)
  const float c2 = 0.2f * s1v - mv;

  f32x4 acc[8], acc_l;
  #pragma unroll
  for (int j = 0; j < 8; j++){ acc[j][0]=0.f; acc[j][1]=0.f; acc[j][2]=0.f; acc[j][3]=0.f; }
  acc_l[0]=0.f; acc_l[1]=0.f; acc_l[2]=0.f; acc_l[3]=0.f;

  const uint4 onesq = make_uint4(0x3F803F80u, 0x3F803F80u, 0x3F803F80u, 0x3F803F80u);
  const bf16x8 onesf = *(const bf16x8*)&onesq;

  // frag-linear B base: F = (co/16 + ot)*64 + t*2 + kk
  const unsigned short* Bbase = WhT + ((size_t)b * 1024 + (co >> 4) * 64) * 512 + lane * 8;

  auto loadB = [&](int t, bf16x8* dst){
    #pragma unroll
    for (int ot = 0; ot < 8; ot++)
      #pragma unroll
      for (int kk = 0; kk < 2; kk++)
        dst[ot * 2 + kk] = *(const bf16x8*)(Bbase + ((size_t)ot * 64 + t * 2 + kk) * 512);
  };

  auto computeP = [&](int t, bf16x8* af){
    #pragma unroll
    for (int kk = 0; kk < 2; kk++){
      unsigned bits = bitsB[prow * 264 + t * 8 + kk * 4 + lhi];
      const float* sp = &s2s[t * 64 + kk * 32 + lhi * 8];
      float4 xa = *(const float4*)sp;
      float4 xb = *(const float4*)(sp + 4);
      float xs[8] = {xa.x, xa.y, xa.z, xa.w, xb.x, xb.y, xb.z, xb.w};
      unsigned pu[8];
      #pragma unroll
      for (int e = 0; e < 8; e++){
        float s2v = xs[e];
        float y = fmaxf(s2v + c1, __builtin_fmaf(0.2f, s2v, c2));
        float p = __builtin_amdgcn_exp2f(y);
        unsigned msel = ((bits >> e) & 1u) ? 0xFFFF0000u : 0u;
        pu[e] = __float_as_uint(p) & msel;       // mask + truncate in one AND
      }
      uint4 q = make_uint4(permpack(pu[1], pu[0]), permpack(pu[3], pu[2]),
                           permpack(pu[5], pu[4]), permpack(pu[7], pu[6]));
      af[kk] = *(bf16x8*)&q;
    }
  };

  auto doMFMA = [&](bf16x8* af, bf16x8* bf){
    #pragma unroll
    for (int kk = 0; kk < 2; kk++){
      acc_l = __builtin_amdgcn_mfma_f32_16x16x32_bf16(af[kk], onesf, acc_l, 0, 0, 0);
      #pragma unroll
      for (int ot = 0; ot < 8; ot++)
        acc[ot] = __builtin_amdgcn_mfma_f32_16x16x32_bf16(af[kk], bf[ot * 2 + kk], acc[ot], 0, 0, 0);
    }
  };

  bf16x8 b0[16], b1[16], af[2];
  loadB(0, b0);
  for (int t = 0; t < 32; t += 2){
    loadB(t + 1, b1);                  // B(t+1) flies during computeP+MFMA(t)
    computeP(t, af);
    doMFMA(af, b0);
    if (t + 2 < 32) loadB(t + 2, b0);  // B(t+2) flies during computeP+MFMA(t+1)
    computeP(t + 1, af);
    doMFMA(af, b1);
  }

  // ---- epilogue: scale by 1/rowsum (acc_l[q] = rowsum of row lhi*4+q) ----
  #pragma unroll
  for (int q = 0; q < 4; q++){
    float lv = 1.0f / acc_l[q];
    int row = i0 + wi * 16 + lhi * 4 + q;
    #pragma unroll
    for (int ot = 0; ot < 8; ot++)
      out[(size_t)(b * NN + row) * 256 + co + ot * 16 + llo] = acc[ot][q] * lv;
  }
}

extern "C" void kernel_launch(void* const* d_in, const int* in_sizes, int n_in,
                              void* d_out, int out_size, void* d_ws, size_t ws_size,
                              hipStream_t stream) {
  const float* h   = (const float*)d_in[0];
  const float* adj = (const float*)d_in[1];
  const float* W   = (const float*)d_in[2];
  const float* a   = (const float*)d_in[3];
  float* out = (float*)d_out;

  char* ws = (char*)d_ws;
  unsigned short* WhT      = (unsigned short*)(ws);                 // 8,388,608 B (frag-linear)
  unsigned short* Wt       = (unsigned short*)(ws + 8388608);       //   131,072 B
  unsigned long long* ab   = (unsigned long long*)(ws + 8519680);   //   524,288 B
  float* s1c               = (float*)(ws + 9043968);                //    65,536 B
  float* s2c               = (float*)(ws + 9109504);                //    65,536 B

  hipLaunchKernelGGL(k_prep,       dim3(2304), dim3(256), 0, stream, adj, W, ab, Wt);
  hipLaunchKernelGGL(k_fused_gemm, dim3(512),  dim3(256), 0, stream, h, Wt, a, WhT, s1c, s2c);
  hipLaunchKernelGGL(k_attn,       dim3(512),  dim3(256), 0, stream, s1c, s2c, WhT, ab, out);
}